// Round 12
// baseline (164.567 us; speedup 1.0000x reference)
//
#include <hip/hip_runtime.h>

#define OUT_HW    14
#define NBINS     196               // 14*14
#define C_TOTAL   256
#define C_PER_BLK 64
#define NQUADS    (C_PER_BLK / 4)   // 16 channel-quads per block
#define NBOXES    512
#define LCELLS    1024              // logical 16B cells per buffer (strict bound ~900)
#define PCELLS    1152              // phys cells after +(c>>3) bank-spread inflation
#define PWORDS    (4 * PCELLS)      // 4608 words = 18 KB per buffer (2 bufs = 36 KB)
#define MAXC      4                 // LCELLS / 256 cells per thread

// bank-spread: insert one dummy cell every 8 -> stride-8-cell aliasing vanishes.
// Strictly increasing => bijective; applied identically on write and read.
__device__ __forceinline__ int physc(int c) { return c + (c >> 3); }

__device__ __forceinline__ void axis_entry(float coord, float L,
                                           int& lo, int& hi, float& wlo, float& whi) {
    // torchvision ROIAlign bilinear edge handling
    const bool valid = (coord >= -1.0f) && (coord <= L);
    const float c   = fminf(fmaxf(coord, 0.0f), L - 1.0f);
    const float flo = floorf(c);
    const float fhi = fminf(flo + 1.0f, L - 1.0f);
    whi = c - flo;
    wlo = 1.0f - whi;
    if (!valid) { wlo = 0.0f; whi = 0.0f; }
    lo = (int)flo;
    hi = (int)fhi;
}

// NOTE: (256,3) not (256,4): the 4-bound clamps the allocator to 64 VGPR ->
// staging regs spill to scratch (+300 MB FETCH, 2.4x slower; rounds 9/10).
__global__ __launch_bounds__(256, 3) void roi_pool_kernel(
    const float* __restrict__ x0, const float* __restrict__ x1,
    const float* __restrict__ x2, const float* __restrict__ x3,
    const float* __restrict__ boxes, float* __restrict__ out)
{
    __shared__ float tile[2][PWORDS];   // 2 x 18 KB = 36 KB

    const int m    = blockIdx.x;   // box
    const int cblk = blockIdx.y;   // 64-channel chunk
    const int tid  = threadIdx.x;

    // ---- block-uniform box/level setup ----
    const float bxi = boxes[m*5+0];
    const float bx0 = boxes[m*5+1];
    const float by0 = boxes[m*5+2];
    const float bx1 = boxes[m*5+3];
    const float by1 = boxes[m*5+4];

    const float sz = sqrtf((bx1 - bx0) * (by1 - by0));
    int lvl = (int)floorf(4.0f + log2f(sz * (1.0f/224.0f) + 1e-8f));
    lvl = min(max(lvl, 2), 5) - 2;

    const float scales[4] = {0.25f, 0.125f, 0.0625f, 0.03125f};
    const int   dims[4]   = {256, 128, 64, 32};
    const float scale = scales[lvl];
    const int   W  = dims[lvl];
    const int   HW = W * W;
    const float Lf = (float)W;
    const float* feat = (lvl == 0) ? x0 : (lvl == 1) ? x1 : (lvl == 2) ? x2 : x3;
    const int bidx = (int)bxi;

    const float rx0 = bx0*scale - 0.5f;
    const float ry0 = by0*scale - 0.5f;
    const float binw = (bx1*scale - 0.5f - rx0) * (1.0f/14.0f);
    const float binh = (by1*scale - 0.5f - ry0) * (1.0f/14.0f);

    // ---- footprint extents (samples are monotone; first lo / last hi) ----
    int ymin, ymax, xmin, xmax;
    {
        int lo, hi; float a, b;
        axis_entry(ry0 +  0.25f*binh, Lf, lo, hi, a, b); ymin = lo;
        axis_entry(ry0 + 13.75f*binh, Lf, lo, hi, a, b); ymax = hi;
        axis_entry(rx0 +  0.25f*binw, Lf, lo, hi, a, b); xmin = lo;
        axis_entry(rx0 + 13.75f*binw, Lf, lo, hi, a, b); xmax = hi;
    }
    const int NR  = ymax - ymin + 1;
    const int TWr = xmax - xmin + 1;

    // ---- separable axis choice: interp the LONGER axis during staging ----
    // A=x (ax=true): intermediate [NR rows][28 x-samples + pad], row stride 29
    // A=y          : intermediate [28 y-sample rows][TWr cols, padded to odd]
    const bool ax = (NR <= TWr);
    int ON = ax ? NR : 28;
    const int S = ax ? 29 : (TWr | 1);          // odd stride rotates bank phase
    if (ON * S > LCELLS) ON = LCELLS / S;       // safety (analysis: never triggers)
    const int TCL = ON * S;                     // logical cells incl. pad slots

    // ---- per-thread staging setup (constant across quads) ----
    int   g0[MAXC], g1[MAXC], lw[MAXC];
    float wa[MAXC], wb[MAXC];
    bool  cv[MAXC];
    #pragma unroll
    for (int s = 0; s < MAXC; ++s) {
        const int e = tid + (s << 8);
        cv[s] = (e < TCL);
        const int ec = min(e, TCL - 1);
        const int o  = ec / S;                  // outer index
        const int i  = ec - o * S;              // inner index (may be pad)
        int lo, hi; float wl, wh;
        if (ax) {
            const int ii = min(i, 27);          // pad slot: harmless duplicate
            const float coord = rx0 + ((float)(ii >> 1) + 0.25f + 0.5f*(float)(ii & 1)) * binw;
            axis_entry(coord, Lf, lo, hi, wl, wh);
            const int row = ymin + o;           // o < NR => in-range
            g0[s] = row * W + lo;               // lo,hi in [0,W-1] => in-plane
            g1[s] = row * W + hi;
        } else {
            const float coord = ry0 + ((float)(o >> 1) + 0.25f + 0.5f*(float)(o & 1)) * binh;
            axis_entry(coord, Lf, lo, hi, wl, wh);
            const int col = xmin + i;           // pad col may be xmax+1
            g0[s] = min(lo * W + col, HW - 1);  // clamp: pad stays in-plane
            g1[s] = min(hi * W + col, HW - 1);
        }
        wa[s] = wl; wb[s] = wh;
        lw[s] = physc(ec) << 2;                 // swizzled dest word
    }

    // ---- per-thread tap setup (bin = thread) ----
    const bool active = (tid < NBINS);
    const int  t  = active ? tid : (NBINS - 1);
    const int  ph = t / OUT_HW;
    const int  pw = t - ph * OUT_HW;

    int yl0, yh0, yl1, yh1, xl0, xh0, xl1, xh1;
    float wy0, wy1, wy2, wy3, wx0, wx1, wx2, wx3;
    axis_entry(ry0 + ((float)ph + 0.25f)*binh, Lf, yl0, yh0, wy0, wy1);
    axis_entry(ry0 + ((float)ph + 0.75f)*binh, Lf, yl1, yh1, wy2, wy3);
    axis_entry(rx0 + ((float)pw + 0.25f)*binw, Lf, xl0, xh0, wx0, wx1);
    axis_entry(rx0 + ((float)pw + 0.75f)*binw, Lf, xl1, xh1, wx2, wx3);

    // tap = sum_k wk * (T[woff(k,0)] + T[woff(k,1)]), 0.25 sample-mean folded in
    float wk[4];
    int   woff[8];
    if (ax) {
        // k -> y rows {yl0,yh0,yl1,yh1}; pairs -> x-samples {2pw, 2pw+1}
        wk[0] = 0.25f*wy0; wk[1] = 0.25f*wy1; wk[2] = 0.25f*wy2; wk[3] = 0.25f*wy3;
        const int rr[4] = { yl0 - ymin, yh0 - ymin, yl1 - ymin, yh1 - ymin };
        #pragma unroll
        for (int k = 0; k < 4; ++k) {
            const int base = rr[k] * S + 2*pw;
            woff[2*k]   = physc(min(base,     TCL - 1)) << 2;
            woff[2*k+1] = physc(min(base + 1, TCL - 1)) << 2;
        }
    } else {
        // k -> x cols {xl0,xh0,xl1,xh1}; pairs -> y-samples {2ph, 2ph+1}
        wk[0] = 0.25f*wx0; wk[1] = 0.25f*wx1; wk[2] = 0.25f*wx2; wk[3] = 0.25f*wx3;
        const int cc[4] = { xl0 - xmin, xh0 - xmin, xl1 - xmin, xh1 - xmin };
        #pragma unroll
        for (int k = 0; k < 4; ++k) {
            woff[2*k]   = physc(min((2*ph)     * S + cc[k], TCL - 1)) << 2;
            woff[2*k+1] = physc(min((2*ph + 1) * S + cc[k], TCL - 1)) << 2;
        }
    }

    const float* fb = feat + ((size_t)bidx * C_TOTAL + (size_t)cblk * C_PER_BLK) * HW;
    float* ob = out + ((size_t)m * C_TOTAL + (size_t)cblk * C_PER_BLK) * NBINS + tid;

    // ---- staging: 8 scalar loads/cell -> interp pair -> ds_write_b128 ----
    float2 stg[MAXC][4];

    auto LOADQ = [&](int qd) {
        const float* f0 = fb + (size_t)qd * 4 * HW;
        const float* f1 = f0 + HW;
        const float* f2 = f1 + HW;
        const float* f3 = f2 + HW;
        #pragma unroll
        for (int s = 0; s < MAXC; ++s) {
            stg[s][0].x = f0[g0[s]]; stg[s][0].y = f0[g1[s]];
            stg[s][1].x = f1[g0[s]]; stg[s][1].y = f1[g1[s]];
            stg[s][2].x = f2[g0[s]]; stg[s][2].y = f2[g1[s]];
            stg[s][3].x = f3[g0[s]]; stg[s][3].y = f3[g1[s]];
        }
    };
    auto WRITEQ = [&](float* dst) {
        #pragma unroll
        for (int s = 0; s < MAXC; ++s)
            if (cv[s]) {
                float4 v;
                v.x = wa[s]*stg[s][0].x + wb[s]*stg[s][0].y;
                v.y = wa[s]*stg[s][1].x + wb[s]*stg[s][1].y;
                v.z = wa[s]*stg[s][2].x + wb[s]*stg[s][2].y;
                v.w = wa[s]*stg[s][3].x + wb[s]*stg[s][3].y;
                *(float4*)(dst + lw[s]) = v;
            }
    };

    // ---- prologue: stage quad 0 into buffer 0 ----
    LOADQ(0);
    WRITEQ(&tile[0][0]);

    // ---- quad loop (round-11 proven schedule) ----
    for (int p = 0; p < NQUADS; ++p) {
        __syncthreads();   // stage(p) visible; all waves done reading buf (p+1)&1
        const bool more = (p + 1 < NQUADS);
        if (more) LOADQ(p + 1);                 // HBM latency hides under compute

        const float* bp = &tile[p & 1][0];
        float vx = 0.0f, vy = 0.0f, vz = 0.0f, vw = 0.0f;
        #pragma unroll
        for (int k = 0; k < 4; ++k) {
            const float4 tA = *(const float4*)(bp + woff[2*k]);
            const float4 tB = *(const float4*)(bp + woff[2*k+1]);
            const float w = wk[k];
            vx += w * (tA.x + tB.x);
            vy += w * (tA.y + tB.y);
            vz += w * (tA.z + tB.z);
            vw += w * (tA.w + tB.w);
        }
        if (active) {
            ob[(size_t)(4*p + 0) * NBINS] = vx;
            ob[(size_t)(4*p + 1) * NBINS] = vy;
            ob[(size_t)(4*p + 2) * NBINS] = vz;
            ob[(size_t)(4*p + 3) * NBINS] = vw;
        }
        if (more) WRITEQ(&tile[(p + 1) & 1][0]);   // drained by the next barrier
    }
}

extern "C" void kernel_launch(void* const* d_in, const int* in_sizes, int n_in,
                              void* d_out, int out_size, void* d_ws, size_t ws_size,
                              hipStream_t stream) {
    const float* x0    = (const float*)d_in[0];
    const float* x1    = (const float*)d_in[1];
    const float* x2    = (const float*)d_in[2];
    const float* x3    = (const float*)d_in[3];
    const float* boxes = (const float*)d_in[4];
    float* out = (float*)d_out;

    dim3 grid(NBOXES, C_TOTAL / C_PER_BLK);
    dim3 block(256);
    roi_pool_kernel<<<grid, block, 0, stream>>>(x0, x1, x2, x3, boxes, out);
}

// Round 13
// 111.423 us; speedup vs baseline: 1.4770x; 1.4770x over previous
//
#include <hip/hip_runtime.h>
#include <stdint.h>

#define OUT_HW    14
#define NBINS     196               // 14*14
#define C_TOTAL   256
#define C_PER_BLK 64
#define NQUADS    (C_PER_BLK / 4)   // 16 channel-quads; quad 0 goes direct-global
#define NBOXES    512
#define BUFQ      1280              // 16B cells per buffer (covers worst footprint ~1210)
#define QWORDS    (4 * BUFQ)        // 5120 words = 20 KB per buffer (2 bufs = 40 KB)
#define MAXC      5                 // BUFQ / 256 cells per thread

__device__ __forceinline__ void axis_entry(float coord, float L,
                                           int& lo, int& hi, float& wlo, float& whi) {
    // torchvision ROIAlign bilinear edge handling
    const bool valid = (coord >= -1.0f) && (coord <= L);
    const float c   = fminf(fmaxf(coord, 0.0f), L - 1.0f);
    const float flo = floorf(c);
    const float fhi = fminf(flo + 1.0f, L - 1.0f);
    whi = c - flo;
    wlo = 1.0f - whi;
    if (!valid) { wlo = 0.0f; whi = 0.0f; }
    lo = (int)flo;
    hi = (int)fhi;
}

// NOTE: (256,3) not (256,4): the 4-bound clamps the allocator to 64 VGPR ->
// staging regs spill to scratch (+300 MB FETCH, 2.4x slower; rounds 9/10).
__global__ __launch_bounds__(256, 3) void roi_pool_kernel(
    const float* __restrict__ x0, const float* __restrict__ x1,
    const float* __restrict__ x2, const float* __restrict__ x3,
    const float* __restrict__ boxes, float* __restrict__ out)
{
    __shared__ float tile[2][QWORDS];   // 2 x 20 KB = 40 KB

    const int m    = blockIdx.x;   // box
    const int cblk = blockIdx.y;   // 64-channel chunk
    const int tid  = threadIdx.x;

    // ---- block-uniform box/level setup ----
    const float bxi = boxes[m*5+0];
    const float bx0 = boxes[m*5+1];
    const float by0 = boxes[m*5+2];
    const float bx1 = boxes[m*5+3];
    const float by1 = boxes[m*5+4];

    const float sz = sqrtf((bx1 - bx0) * (by1 - by0));
    int lvl = (int)floorf(4.0f + log2f(sz * (1.0f/224.0f) + 1e-8f));
    lvl = min(max(lvl, 2), 5) - 2;

    const float scales[4] = {0.25f, 0.125f, 0.0625f, 0.03125f};
    const int   dims[4]   = {256, 128, 64, 32};
    const float scale = scales[lvl];
    const int   W  = dims[lvl];
    const int   HW = W * W;
    const float Lf = (float)W;
    const float* feat = (lvl == 0) ? x0 : (lvl == 1) ? x1 : (lvl == 2) ? x2 : x3;
    const int bidx = (int)bxi;

    const float rx0 = bx0*scale - 0.5f;
    const float ry0 = by0*scale - 0.5f;
    const float binw = (bx1*scale - 0.5f - rx0) * (1.0f/14.0f);
    const float binh = (by1*scale - 0.5f - ry0) * (1.0f/14.0f);

    // ---- footprint extents (samples are monotone; first lo / last hi) ----
    int ymin, ymax, xmin, xmax;
    {
        int lo, hi; float a, b;
        axis_entry(ry0 +  0.25f*binh, Lf, lo, hi, a, b); ymin = lo;
        axis_entry(ry0 + 13.75f*binh, Lf, lo, hi, a, b); ymax = hi;
        axis_entry(rx0 +  0.25f*binw, Lf, lo, hi, a, b); xmin = lo;
        axis_entry(rx0 + 13.75f*binw, Lf, lo, hi, a, b); xmax = hi;
    }
    const int TW = (xmax - xmin + 1) | 1;          // ODD cell stride: rotates bank phase per row
    int NR = ymax - ymin + 1;                      // tile rows
    if (NR * TW > BUFQ) NR = BUFQ / TW;            // safety cap (analysis: never triggers)
    const int TC = NR * TW;                        // cells (16B each) per quad tile

    // ---- per-thread cell slots (constant across quads); pure row-major layout ----
    int  gw[MAXC], lw[MAXC];
    bool cv[MAXC];
    #pragma unroll
    for (int s = 0; s < MAXC; ++s) {
        const int cell = tid + (s << 8);
        cv[s] = (cell < TC);
        const int cl = min(cell, TC - 1);
        const int r  = cl / TW;
        const int c  = cl - r * TW;
        gw[s] = min((ymin + r) * W + xmin + c, HW - 1);   // clamp: pad cols stay in-plane
        lw[s] = cl << 2;                                   // linear dest word (cell*4)
    }

    // ---- per-thread tap setup (bin = thread) ----
    const bool active = (tid < NBINS);
    const int  t  = active ? tid : (NBINS - 1);
    const int  ph = t / OUT_HW;
    const int  pw = t - ph * OUT_HW;

    int yl0, yh0, yl1, yh1, xl0, xh0, xl1, xh1;
    float wy0, wy1, wy2, wy3, wx0, wx1, wx2, wx3;
    axis_entry(ry0 + ((float)ph + 0.25f)*binh, Lf, yl0, yh0, wy0, wy1);
    axis_entry(ry0 + ((float)ph + 0.75f)*binh, Lf, yl1, yh1, wy2, wy3);
    axis_entry(rx0 + ((float)pw + 0.25f)*binw, Lf, xl0, xh0, wx0, wx1);
    axis_entry(rx0 + ((float)pw + 0.75f)*binw, Lf, xl1, xh1, wx2, wx3);
    wy0 *= 0.25f; wy1 *= 0.25f; wy2 *= 0.25f; wy3 *= 0.25f;  // fold 2x2 mean
    const float wyv[4] = { wy0, wy1, wy2, wy3 };

    const int sr[4] = { yl0 - ymin, yh0 - ymin, yl1 - ymin, yh1 - ymin };
    const int sc[4] = { xl0 - xmin, xh0 - xmin, xl1 - xmin, xh1 - xmin };

    int wq[16];   // LDS tap cell indices (16B units), row-major
    #pragma unroll
    for (int i = 0; i < 4; ++i) {
        #pragma unroll
        for (int j = 0; j < 4; ++j) {
            wq[i*4 + j] = min(sr[i] * TW + sc[j], TC - 1);
        }
    }

    const float* fb = feat + ((size_t)bidx * C_TOTAL + (size_t)cblk * C_PER_BLK) * HW;
    float* ob = out + ((size_t)m * C_TOTAL + (size_t)cblk * C_PER_BLK) * NBINS + tid;

    // ---- staging: plain loads -> registers -> ds_write_b128 ----
    float4 stg[MAXC];

    auto LOADQ = [&](int qd) {
        const float* f0 = fb + (size_t)qd * 4 * HW;
        const float* f1 = f0 + HW;
        const float* f2 = f1 + HW;
        const float* f3 = f2 + HW;
        #pragma unroll
        for (int s = 0; s < MAXC; ++s) {
            float4 v;
            v.x = f0[gw[s]];
            v.y = f1[gw[s]];
            v.z = f2[gw[s]];
            v.w = f3[gw[s]];
            stg[s] = v;
        }
    };
    auto WRITEQ = [&](float* dst) {
        #pragma unroll
        for (int s = 0; s < MAXC; ++s)
            if (cv[s]) *(float4*)(dst + lw[s]) = stg[s];
    };

    // ---- prologue: stage quad 1 into buffer 1; quad 0 (ch 0-3) via direct
    //      global taps (VMEM pipe) while the staging loads are in flight ----
    LOADQ(1);
    {   // quad 0: 16 scattered global taps per channel (round-1 compute).
        // Offsets scoped here so their VGPRs die before the main loop.
        const int yy[4] = { yl0, yh0, yl1, yh1 };
        const int xx[4] = { xl0, xh0, xl1, xh1 };
        const float wxv[4] = { wx0, wx1, wx2, wx3 };
        #pragma unroll
        for (int ch = 0; ch < 4; ++ch) {
            const float* f = fb + (size_t)ch * HW;
            float a = 0.0f;
            #pragma unroll
            for (int i = 0; i < 4; ++i) {
                const int rb = yy[i] * W;
                a += wyv[i] * (wxv[0] * f[rb + xx[0]] + wxv[1] * f[rb + xx[1]] +
                               wxv[2] * f[rb + xx[2]] + wxv[3] * f[rb + xx[3]]);
            }
            if (active) ob[(size_t)ch * NBINS] = a;
        }
    }
    WRITEQ(&tile[1][0]);

    // ---- quad loop p = 1..15 (round-11 proven schedule, shifted start) ----
    for (int p = 1; p < NQUADS; ++p) {
        __syncthreads();   // stage(p) visible; all waves done reading buf (p+1)&1
        const bool more = (p + 1 < NQUADS);
        if (more) LOADQ(p + 1);                 // HBM latency hides under compute below

        const float* bp = &tile[p & 1][0];
        float vx = 0.0f, vy = 0.0f, vz = 0.0f, vw = 0.0f;
        #pragma unroll
        for (int i = 0; i < 4; ++i) {
            const float4 t0 = *(const float4*)(bp + (wq[4*i + 0] << 2));
            const float4 t1 = *(const float4*)(bp + (wq[4*i + 1] << 2));
            const float4 t2 = *(const float4*)(bp + (wq[4*i + 2] << 2));
            const float4 t3 = *(const float4*)(bp + (wq[4*i + 3] << 2));
            const float wyi = wyv[i];
            vx += wyi * (wx0*t0.x + wx1*t1.x + wx2*t2.x + wx3*t3.x);
            vy += wyi * (wx0*t0.y + wx1*t1.y + wx2*t2.y + wx3*t3.y);
            vz += wyi * (wx0*t0.z + wx1*t1.z + wx2*t2.z + wx3*t3.z);
            vw += wyi * (wx0*t0.w + wx1*t1.w + wx2*t2.w + wx3*t3.w);
        }
        if (active) {
            ob[(size_t)(4*p + 0) * NBINS] = vx;
            ob[(size_t)(4*p + 1) * NBINS] = vy;
            ob[(size_t)(4*p + 2) * NBINS] = vz;
            ob[(size_t)(4*p + 3) * NBINS] = vw;
        }
        if (more) WRITEQ(&tile[(p + 1) & 1][0]);   // drained by the next barrier
    }
}

extern "C" void kernel_launch(void* const* d_in, const int* in_sizes, int n_in,
                              void* d_out, int out_size, void* d_ws, size_t ws_size,
                              hipStream_t stream) {
    const float* x0    = (const float*)d_in[0];
    const float* x1    = (const float*)d_in[1];
    const float* x2    = (const float*)d_in[2];
    const float* x3    = (const float*)d_in[3];
    const float* boxes = (const float*)d_in[4];
    float* out = (float*)d_out;

    dim3 grid(NBOXES, C_TOTAL / C_PER_BLK);
    dim3 block(256);
    roi_pool_kernel<<<grid, block, 0, stream>>>(x0, x1, x2, x3, boxes, out);
}

// Round 14
// 92.595 us; speedup vs baseline: 1.7773x; 1.2033x over previous
//
#include <hip/hip_runtime.h>
#include <stdint.h>

#define OUT_HW    14
#define NBINS     196               // 14*14
#define C_TOTAL   256
#define C_PER_BLK 64
#define NQUADS    (C_PER_BLK / 4)   // 16 channel-quads per block
#define NBOXES    512
#define BUFQ      1280              // 8B cells per buffer (worst footprint ~1020)
#define MAXC      5                 // BUFQ / 256 cells per thread

__device__ __forceinline__ void axis_entry(float coord, float L,
                                           int& lo, int& hi, float& wlo, float& whi) {
    // torchvision ROIAlign bilinear edge handling
    const bool valid = (coord >= -1.0f) && (coord <= L);
    const float c   = fminf(fmaxf(coord, 0.0f), L - 1.0f);
    const float flo = floorf(c);
    const float fhi = fminf(flo + 1.0f, L - 1.0f);
    whi = c - flo;
    wlo = 1.0f - whi;
    if (!valid) { wlo = 0.0f; whi = 0.0f; }
    lo = (int)flo;
    hi = (int)fhi;
}

// pack two f32 -> two bf16 (round-to-nearest-even), lanes: lo=a, hi=b
__device__ __forceinline__ unsigned pack_bf16(float a, float b) {
    unsigned ua = __float_as_uint(a);
    unsigned ub = __float_as_uint(b);
    ua += 0x7FFFu + ((ua >> 16) & 1u);
    ub += 0x7FFFu + ((ub >> 16) & 1u);
    return (ua >> 16) | (ub & 0xFFFF0000u);
}
__device__ __forceinline__ float lo16(unsigned u) { return __uint_as_float(u << 16); }
__device__ __forceinline__ float hi16(unsigned u) { return __uint_as_float(u & 0xFFFF0000u); }

// NOTE: (256,3) not (256,4): the 4-bound clamps the allocator to 64 VGPR ->
// staging regs spill to scratch (+300 MB FETCH, 2.4x slower; rounds 9/10).
__global__ __launch_bounds__(256, 3) void roi_pool_kernel(
    const float* __restrict__ x0, const float* __restrict__ x1,
    const float* __restrict__ x2, const float* __restrict__ x3,
    const float* __restrict__ boxes, float* __restrict__ out)
{
    __shared__ uint2 tile[2][BUFQ];   // bf16x4 cells: 2 x 10 KB = 20 KB

    const int m    = blockIdx.x;   // box
    const int cblk = blockIdx.y;   // 64-channel chunk
    const int tid  = threadIdx.x;

    // ---- block-uniform box/level setup ----
    const float bxi = boxes[m*5+0];
    const float bx0 = boxes[m*5+1];
    const float by0 = boxes[m*5+2];
    const float bx1 = boxes[m*5+3];
    const float by1 = boxes[m*5+4];

    const float sz = sqrtf((bx1 - bx0) * (by1 - by0));
    int lvl = (int)floorf(4.0f + log2f(sz * (1.0f/224.0f) + 1e-8f));
    lvl = min(max(lvl, 2), 5) - 2;

    const float scales[4] = {0.25f, 0.125f, 0.0625f, 0.03125f};
    const int   dims[4]   = {256, 128, 64, 32};
    const float scale = scales[lvl];
    const int   W  = dims[lvl];
    const int   HW = W * W;
    const float Lf = (float)W;
    const float* feat = (lvl == 0) ? x0 : (lvl == 1) ? x1 : (lvl == 2) ? x2 : x3;
    const int bidx = (int)bxi;

    const float rx0 = bx0*scale - 0.5f;
    const float ry0 = by0*scale - 0.5f;
    const float binw = (bx1*scale - 0.5f - rx0) * (1.0f/14.0f);
    const float binh = (by1*scale - 0.5f - ry0) * (1.0f/14.0f);

    // ---- footprint extents (samples are monotone; first lo / last hi) ----
    int ymin, ymax, xmin, xmax;
    {
        int lo, hi; float a, b;
        axis_entry(ry0 +  0.25f*binh, Lf, lo, hi, a, b); ymin = lo;
        axis_entry(ry0 + 13.75f*binh, Lf, lo, hi, a, b); ymax = hi;
        axis_entry(rx0 +  0.25f*binw, Lf, lo, hi, a, b); xmin = lo;
        axis_entry(rx0 + 13.75f*binw, Lf, lo, hi, a, b); xmax = hi;
    }
    const int TW = (xmax - xmin + 1) | 1;          // ODD cell stride: rotates bank phase per row
    int NR = ymax - ymin + 1;                      // tile rows
    if (NR * TW > BUFQ) NR = BUFQ / TW;            // safety cap (analysis: never triggers)
    const int TC = NR * TW;                        // cells (8B each) per quad tile

    // ---- per-thread cell slots (constant across quads); pure row-major layout ----
    int  gw[MAXC], lw[MAXC];
    bool cv[MAXC];
    #pragma unroll
    for (int s = 0; s < MAXC; ++s) {
        const int cell = tid + (s << 8);
        cv[s] = (cell < TC);
        const int cl = min(cell, TC - 1);
        const int r  = cl / TW;
        const int c  = cl - r * TW;
        gw[s] = min((ymin + r) * W + xmin + c, HW - 1);   // clamp: pad cols stay in-plane
        lw[s] = cl;                                        // cell index (uint2 units)
    }

    // ---- per-thread tap setup (bin = thread) ----
    const bool active = (tid < NBINS);
    const int  t  = active ? tid : (NBINS - 1);
    const int  ph = t / OUT_HW;
    const int  pw = t - ph * OUT_HW;

    int yl0, yh0, yl1, yh1, xl0, xh0, xl1, xh1;
    float wy0, wy1, wy2, wy3, wx0, wx1, wx2, wx3;
    axis_entry(ry0 + ((float)ph + 0.25f)*binh, Lf, yl0, yh0, wy0, wy1);
    axis_entry(ry0 + ((float)ph + 0.75f)*binh, Lf, yl1, yh1, wy2, wy3);
    axis_entry(rx0 + ((float)pw + 0.25f)*binw, Lf, xl0, xh0, wx0, wx1);
    axis_entry(rx0 + ((float)pw + 0.75f)*binw, Lf, xl1, xh1, wx2, wx3);
    wy0 *= 0.25f; wy1 *= 0.25f; wy2 *= 0.25f; wy3 *= 0.25f;  // fold 2x2 mean
    const float wyv[4] = { wy0, wy1, wy2, wy3 };

    const int sr[4] = { yl0 - ymin, yh0 - ymin, yl1 - ymin, yh1 - ymin };
    const int sc[4] = { xl0 - xmin, xh0 - xmin, xl1 - xmin, xh1 - xmin };

    int wq[16];   // tap cell indices, row-major
    #pragma unroll
    for (int i = 0; i < 4; ++i) {
        #pragma unroll
        for (int j = 0; j < 4; ++j) {
            wq[i*4 + j] = min(sr[i] * TW + sc[j], TC - 1);
        }
    }

    const float* fb = feat + ((size_t)bidx * C_TOTAL + (size_t)cblk * C_PER_BLK) * HW;
    float* ob = out + ((size_t)m * C_TOTAL + (size_t)cblk * C_PER_BLK) * NBINS + tid;

    // ---- staging: plain loads -> registers -> pack bf16 -> ds_write_b64 ----
    float4 stg[MAXC];

    auto LOADQ = [&](int qd) {
        const float* f0 = fb + (size_t)qd * 4 * HW;
        const float* f1 = f0 + HW;
        const float* f2 = f1 + HW;
        const float* f3 = f2 + HW;
        #pragma unroll
        for (int s = 0; s < MAXC; ++s) {
            float4 v;
            v.x = f0[gw[s]];
            v.y = f1[gw[s]];
            v.z = f2[gw[s]];
            v.w = f3[gw[s]];
            stg[s] = v;
        }
    };
    auto WRITEQ = [&](uint2* dst) {
        #pragma unroll
        for (int s = 0; s < MAXC; ++s)
            if (cv[s]) {
                uint2 w;
                w.x = pack_bf16(stg[s].x, stg[s].y);
                w.y = pack_bf16(stg[s].z, stg[s].w);
                dst[lw[s]] = w;
            }
    };

    // ---- prologue: stage quad 0 into buffer 0 ----
    LOADQ(0);
    WRITEQ(&tile[0][0]);

    // ---- quad loop (round-11 proven schedule) ----
    for (int p = 0; p < NQUADS; ++p) {
        __syncthreads();   // stage(p) visible; all waves done reading buf (p+1)&1
        const bool more = (p + 1 < NQUADS);
        if (more) LOADQ(p + 1);                 // HBM latency hides under compute below

        const uint2* bp = &tile[p & 1][0];
        float vx = 0.0f, vy = 0.0f, vz = 0.0f, vw = 0.0f;
        #pragma unroll
        for (int i = 0; i < 4; ++i) {
            const uint2 c0 = bp[wq[4*i + 0]];
            const uint2 c1 = bp[wq[4*i + 1]];
            const uint2 c2 = bp[wq[4*i + 2]];
            const uint2 c3 = bp[wq[4*i + 3]];
            const float wyi = wyv[i];
            vx += wyi * (wx0*lo16(c0.x) + wx1*lo16(c1.x) + wx2*lo16(c2.x) + wx3*lo16(c3.x));
            vy += wyi * (wx0*hi16(c0.x) + wx1*hi16(c1.x) + wx2*hi16(c2.x) + wx3*hi16(c3.x));
            vz += wyi * (wx0*lo16(c0.y) + wx1*lo16(c1.y) + wx2*lo16(c2.y) + wx3*lo16(c3.y));
            vw += wyi * (wx0*hi16(c0.y) + wx1*hi16(c1.y) + wx2*hi16(c2.y) + wx3*hi16(c3.y));
        }
        if (active) {
            ob[(size_t)(4*p + 0) * NBINS] = vx;
            ob[(size_t)(4*p + 1) * NBINS] = vy;
            ob[(size_t)(4*p + 2) * NBINS] = vz;
            ob[(size_t)(4*p + 3) * NBINS] = vw;
        }
        if (more) WRITEQ(&tile[(p + 1) & 1][0]);   // drained by the next barrier
    }
}

extern "C" void kernel_launch(void* const* d_in, const int* in_sizes, int n_in,
                              void* d_out, int out_size, void* d_ws, size_t ws_size,
                              hipStream_t stream) {
    const float* x0    = (const float*)d_in[0];
    const float* x1    = (const float*)d_in[1];
    const float* x2    = (const float*)d_in[2];
    const float* x3    = (const float*)d_in[3];
    const float* boxes = (const float*)d_in[4];
    float* out = (float*)d_out;

    dim3 grid(NBOXES, C_TOTAL / C_PER_BLK);
    dim3 block(256);
    roi_pool_kernel<<<grid, block, 0, stream>>>(x0, x1, x2, x3, boxes, out);
}

// Round 16
// 85.086 us; speedup vs baseline: 1.9341x; 1.0883x over previous
//
#include <hip/hip_runtime.h>
#include <stdint.h>

#define OUT_HW    14
#define NBINS     196               // 14*14
#define C_TOTAL   256
#define C_PER_BLK 64
#define NQUADS    (C_PER_BLK / 4)   // 16 channel-quads per block
#define NBOXES    512
#define BUFL      1792              // 8B cells per buffer (worst footprint ~1638: lvl-0 tall box)
#define MAXG      2                 // groups (4 cells) per thread: worst NG ~378 < 512

__device__ __forceinline__ void axis_entry(float coord, float L,
                                           int& lo, int& hi, float& wlo, float& whi) {
    // torchvision ROIAlign bilinear edge handling
    const bool valid = (coord >= -1.0f) && (coord <= L);
    const float c   = fminf(fmaxf(coord, 0.0f), L - 1.0f);
    const float flo = floorf(c);
    const float fhi = fminf(flo + 1.0f, L - 1.0f);
    whi = c - flo;
    wlo = 1.0f - whi;
    if (!valid) { wlo = 0.0f; whi = 0.0f; }
    lo = (int)flo;
    hi = (int)fhi;
}

// pack two f32 -> two bf16 (round-to-nearest-even), lanes: lo=a, hi=b
__device__ __forceinline__ unsigned pack_bf16(float a, float b) {
    unsigned ua = __float_as_uint(a);
    unsigned ub = __float_as_uint(b);
    ua += 0x7FFFu + ((ua >> 16) & 1u);
    ub += 0x7FFFu + ((ub >> 16) & 1u);
    return (ua >> 16) | (ub & 0xFFFF0000u);
}
__device__ __forceinline__ float lo16(unsigned u) { return __uint_as_float(u << 16); }
__device__ __forceinline__ float hi16(unsigned u) { return __uint_as_float(u & 0xFFFF0000u); }

// NOTE: (256,3) not (256,4): the 4-bound clamps the allocator to 64 VGPR ->
// staging regs spill to scratch (+300 MB FETCH, 2.4x slower; rounds 9/10).
__global__ __launch_bounds__(256, 3) void roi_pool_kernel(
    const float* __restrict__ x0, const float* __restrict__ x1,
    const float* __restrict__ x2, const float* __restrict__ x3,
    const float* __restrict__ boxes, float* __restrict__ out)
{
    __shared__ uint2 tile[2][BUFL];   // bf16x4 cells: 2 x 14 KB = 28 KB

    const int m    = blockIdx.x;   // box
    const int cblk = blockIdx.y;   // 64-channel chunk
    const int tid  = threadIdx.x;

    // ---- block-uniform box/level setup ----
    const float bxi = boxes[m*5+0];
    const float bx0 = boxes[m*5+1];
    const float by0 = boxes[m*5+2];
    const float bx1 = boxes[m*5+3];
    const float by1 = boxes[m*5+4];

    const float sz = sqrtf((bx1 - bx0) * (by1 - by0));
    int lvl = (int)floorf(4.0f + log2f(sz * (1.0f/224.0f) + 1e-8f));
    lvl = min(max(lvl, 2), 5) - 2;

    const float scales[4] = {0.25f, 0.125f, 0.0625f, 0.03125f};
    const int   dims[4]   = {256, 128, 64, 32};
    const float scale = scales[lvl];
    const int   W  = dims[lvl];
    const int   HW = W * W;
    const float Lf = (float)W;
    const float* feat = (lvl == 0) ? x0 : (lvl == 1) ? x1 : (lvl == 2) ? x2 : x3;
    const int bidx = (int)bxi;

    const float rx0 = bx0*scale - 0.5f;
    const float ry0 = by0*scale - 0.5f;
    const float binw = (bx1*scale - 0.5f - rx0) * (1.0f/14.0f);
    const float binh = (by1*scale - 0.5f - ry0) * (1.0f/14.0f);

    // ---- footprint extents (samples are monotone; first lo / last hi) ----
    int ymin, ymax, xmin, xmax;
    {
        int lo, hi; float a, b;
        axis_entry(ry0 +  0.25f*binh, Lf, lo, hi, a, b); ymin = lo;
        axis_entry(ry0 + 13.75f*binh, Lf, lo, hi, a, b); ymax = hi;
        axis_entry(rx0 +  0.25f*binw, Lf, lo, hi, a, b); xmin = lo;
        axis_entry(rx0 + 13.75f*binw, Lf, lo, hi, a, b); xmax = hi;
    }
    const int gx  = xmin & ~3;                     // 16B-aligned window start (W % 4 == 0)
    const int TW  = (xmax - gx + 1 + 3) & ~3;      // cols, multiple of 4 (float4 groups)
    const int TW4 = TW >> 2;                       // groups per row
    const int TWL = TW + 1;                        // LDS row stride: odd -> bank rotation
    int NR = ymax - ymin + 1;                      // tile rows
    if (NR * TWL > BUFL) NR = BUFL / TWL;          // safety cap (analysis: never triggers at 1792)
    const int NG  = NR * TW4;                      // global float4 groups per plane
    const int TCL = NR * TWL;                      // LDS cells incl. row pad
    const int CMAX = TCL - 2;                      // last REAL cell ((NR-1)*TWL + TW-1); pad = TCL-1

    // ---- per-thread staging groups (constant across quads) ----
    int  gbase[MAXG];   // global word offset of the 4-cell group (16B aligned)
    int  lbase[MAXG];   // LDS cell index of the group start
    bool gv[MAXG];
    #pragma unroll
    for (int s = 0; s < MAXG; ++s) {
        const int g = tid + (s << 8);
        gv[s] = (g < NG);
        const int gc = min(g, NG - 1);
        const int r  = gc / TW4;
        const int c4 = (gc - r * TW4) << 2;
        gbase[s] = min((ymin + r) * W + gx + c4, HW - 4);  // safety; in-row by alignment proof
        lbase[s] = r * TWL + c4;
    }

    // ---- per-thread tap setup (bin = thread) ----
    const bool active = (tid < NBINS);
    const int  t  = active ? tid : (NBINS - 1);
    const int  ph = t / OUT_HW;
    const int  pw = t - ph * OUT_HW;

    int yl0, yh0, yl1, yh1, xl0, xh0, xl1, xh1;
    float wy0, wy1, wy2, wy3, wx0, wx1, wx2, wx3;
    axis_entry(ry0 + ((float)ph + 0.25f)*binh, Lf, yl0, yh0, wy0, wy1);
    axis_entry(ry0 + ((float)ph + 0.75f)*binh, Lf, yl1, yh1, wy2, wy3);
    axis_entry(rx0 + ((float)pw + 0.25f)*binw, Lf, xl0, xh0, wx0, wx1);
    axis_entry(rx0 + ((float)pw + 0.75f)*binw, Lf, xl1, xh1, wx2, wx3);
    wy0 *= 0.25f; wy1 *= 0.25f; wy2 *= 0.25f; wy3 *= 0.25f;  // fold 2x2 mean
    const float wyv[4] = { wy0, wy1, wy2, wy3 };

    const int sr[4] = { yl0 - ymin, yh0 - ymin, yl1 - ymin, yh1 - ymin };
    const int sc[4] = { xl0 - gx, xh0 - gx, xl1 - gx, xh1 - gx };

    int wq[16];   // tap cell indices; clamp targets a WRITTEN cell (never the row pad)
    #pragma unroll
    for (int i = 0; i < 4; ++i) {
        #pragma unroll
        for (int j = 0; j < 4; ++j) {
            wq[i*4 + j] = min(sr[i] * TWL + sc[j], CMAX);
        }
    }

    const float* fb = feat + ((size_t)bidx * C_TOTAL + (size_t)cblk * C_PER_BLK) * HW;
    float* ob = out + ((size_t)m * C_TOTAL + (size_t)cblk * C_PER_BLK) * NBINS + tid;

    // ---- staging: coalesced float4 loads -> pack bf16 -> b64 cell writes ----
    float4 stg[MAXG][4];   // [group][channel]

    auto LOADQ = [&](int qd) {
        const float* f0 = fb + (size_t)qd * 4 * HW;
        const float* f1 = f0 + HW;
        const float* f2 = f1 + HW;
        const float* f3 = f2 + HW;
        #pragma unroll
        for (int s = 0; s < MAXG; ++s) {
            stg[s][0] = *(const float4*)(f0 + gbase[s]);
            stg[s][1] = *(const float4*)(f1 + gbase[s]);
            stg[s][2] = *(const float4*)(f2 + gbase[s]);
            stg[s][3] = *(const float4*)(f3 + gbase[s]);
        }
    };
    auto WRITEQ = [&](uint2* dst) {
        #pragma unroll
        for (int s = 0; s < MAXG; ++s)
            if (gv[s]) {
                uint2* d = dst + lbase[s];
                d[0] = make_uint2(pack_bf16(stg[s][0].x, stg[s][1].x),
                                  pack_bf16(stg[s][2].x, stg[s][3].x));
                d[1] = make_uint2(pack_bf16(stg[s][0].y, stg[s][1].y),
                                  pack_bf16(stg[s][2].y, stg[s][3].y));
                d[2] = make_uint2(pack_bf16(stg[s][0].z, stg[s][1].z),
                                  pack_bf16(stg[s][2].z, stg[s][3].z));
                d[3] = make_uint2(pack_bf16(stg[s][0].w, stg[s][1].w),
                                  pack_bf16(stg[s][2].w, stg[s][3].w));
            }
    };

    // ---- prologue: stage quad 0 into buffer 0 ----
    LOADQ(0);
    WRITEQ(&tile[0][0]);

    // ---- quad loop (round-11 proven schedule) ----
    for (int p = 0; p < NQUADS; ++p) {
        __syncthreads();   // stage(p) visible; all waves done reading buf (p+1)&1
        const bool more = (p + 1 < NQUADS);
        if (more) LOADQ(p + 1);                 // HBM latency hides under compute below

        const uint2* bp = &tile[p & 1][0];
        float vx = 0.0f, vy = 0.0f, vz = 0.0f, vw = 0.0f;
        #pragma unroll
        for (int i = 0; i < 4; ++i) {
            const uint2 c0 = bp[wq[4*i + 0]];
            const uint2 c1 = bp[wq[4*i + 1]];
            const uint2 c2 = bp[wq[4*i + 2]];
            const uint2 c3 = bp[wq[4*i + 3]];
            const float wyi = wyv[i];
            vx += wyi * (wx0*lo16(c0.x) + wx1*lo16(c1.x) + wx2*lo16(c2.x) + wx3*lo16(c3.x));
            vy += wyi * (wx0*hi16(c0.x) + wx1*hi16(c1.x) + wx2*hi16(c2.x) + wx3*hi16(c3.x));
            vz += wyi * (wx0*lo16(c0.y) + wx1*lo16(c1.y) + wx2*lo16(c2.y) + wx3*lo16(c3.y));
            vw += wyi * (wx0*hi16(c0.y) + wx1*hi16(c1.y) + wx2*hi16(c2.y) + wx3*hi16(c3.y));
        }
        if (active) {
            ob[(size_t)(4*p + 0) * NBINS] = vx;
            ob[(size_t)(4*p + 1) * NBINS] = vy;
            ob[(size_t)(4*p + 2) * NBINS] = vz;
            ob[(size_t)(4*p + 3) * NBINS] = vw;
        }
        if (more) WRITEQ(&tile[(p + 1) & 1][0]);   // drained by the next barrier
    }
}

extern "C" void kernel_launch(void* const* d_in, const int* in_sizes, int n_in,
                              void* d_out, int out_size, void* d_ws, size_t ws_size,
                              hipStream_t stream) {
    const float* x0    = (const float*)d_in[0];
    const float* x1    = (const float*)d_in[1];
    const float* x2    = (const float*)d_in[2];
    const float* x3    = (const float*)d_in[3];
    const float* boxes = (const float*)d_in[4];
    float* out = (float*)d_out;

    dim3 grid(NBOXES, C_TOTAL / C_PER_BLK);
    dim3 block(256);
    roi_pool_kernel<<<grid, block, 0, stream>>>(x0, x1, x2, x3, boxes, out);
}